// Round 10
// baseline (3508.485 us; speedup 1.0000x reference)
//
#include <hip/hip_runtime.h>
#include <math.h>

#define HH 128
#define WW 128
#define CIN 512
#define NPIX 16384
#define NPRE 6000
#define NPOST 300

// workspace offsets (floats; WT64/LOG are doubles at even offsets)
#define WS_WT64   0ull                        // 2359296 doubles = 4718592 floats
#define WS_LOG    4718592ull                  // 16384*12 doubles = 393216 floats
#define WS_FG32   5111808ull                  // 16384
#define WS_ASCALE 5128192ull                  // 16384
#define WS_ASSIGN 5144576ull                  // 16384 (int)
#define WS_ROI    5160960ull                  // 16384*4
#define WS_SC32   5226496ull                  // 16384
#define WS_CAND   5242880ull                  // 6000*4
#define WS_TOPS   5266880ull                  // 6000

// d_out offsets (floats), concatenated tuple in return order
#define O_LOCS   0
#define O_ROIS   65536
#define O_RIDX   66736
#define O_ANCHOR 67036
#define O_CLS    132572
#define O_COS    247260
#define O_RSC    263644
#define O_OLD    263944

__device__ __forceinline__ float exp32(float x) { return (float)exp((double)x); }
__device__ __forceinline__ float sqrt32(float x) { return (float)sqrt((double)x); }

__global__ __launch_bounds__(1024) void zero_kernel(double* __restrict__ p, int n) {
  int i = blockIdx.x * 1024 + threadIdx.x;
  if (i < n) p[i] = 0.0;
}

// ------- weight transpose+convert: w[m][c][k] (f32) -> wt64[(c*9+k)][m] (f64) --
__global__ __launch_bounds__(256) void wt_kernel(const float* __restrict__ w,
                                                 double* __restrict__ wt64) {
  __shared__ float t[64][65];
  int ck0 = blockIdx.x * 64;
  int m0  = blockIdx.y * 64;
  int j  = threadIdx.x & 63;
  int i0 = threadIdx.x >> 6;
#pragma unroll
  for (int ii = 0; ii < 16; ++ii) {
    int i = i0 + ii * 4;
    t[i][j] = w[(size_t)(m0 + i) * 4608 + ck0 + j];
  }
  __syncthreads();
#pragma unroll
  for (int ii = 0; ii < 16; ++ii) {
    int jj = i0 + ii * 4;
    wt64[(size_t)(ck0 + jj) * 512 + m0 + j] = (double)t[j][jj];
  }
}

// -- fused conv 3x3 (fp64 acc, bit-identical (c,ky,kx) chain) on ACTIVE pixels
// -- only (mask==1), then fp32 h epilogue + 12 head dots -> f64 atomics --------
#define KC 8
__global__ __launch_bounds__(256) void conv_heads_kernel(
    const float* __restrict__ x, const double* __restrict__ wt64,
    const float* __restrict__ bias, const int* __restrict__ mask,
    const float* __restrict__ loc_w, const float* __restrict__ cls_w,
    const float* __restrict__ cos_w, double* __restrict__ logits) {
  __shared__ double xs[KC][3][66];   // 12.7 KB
  __shared__ double wsm[KC][9][64];  // 36.9 KB
  __shared__ float w12[12][64];      // 3 KB
  __shared__ int act[64];
  __shared__ int nact_s;
  int tid = threadIdx.x;
  int tm = tid & 15, tp = tid >> 4;
  int seg = blockIdx.x;  // 0..255
  int mt = blockIdx.y;   // 0..7
  int y = seg >> 1, xb = (seg & 1) << 6;
  int m0 = mt << 6;
  int mo = tm << 2;

  for (int idx = tid; idx < 12 * 64; idx += 256) {
    int r = idx >> 6, c = idx & 63;
    float v = (r < 4) ? loc_w[r * 512 + m0 + c]
                      : (r < 11) ? cls_w[(r - 4) * 512 + m0 + c] : cos_w[m0 + c];
    w12[r][c] = v;
  }
  if (tid < 64) {
    int mval = mask[y * WW + xb + tid];
    unsigned long long bal = __ballot(mval != 0);
    if (mval) {
      int pos = __popcll(bal & ((1ull << tid) - 1ull));
      act[pos] = tid;
    }
    if (tid == 0) nact_s = (int)__popcll(bal);
  }
  __syncthreads();
  int n_act = nact_s;
  int np = 0;
  int axr[4] = {0, 0, 0, 0};
#pragma unroll
  for (int ip = 0; ip < 4; ++ip) {
    int slot = tp + (ip << 4);
    if (slot < n_act) { axr[ip] = act[slot]; np = ip + 1; }
  }

  double acc[4][4];
#pragma unroll
  for (int a = 0; a < 4; ++a)
#pragma unroll
    for (int b = 0; b < 4; ++b) acc[a][b] = 0.0;

  for (int c0 = 0; c0 < CIN; c0 += KC) {
    for (int idx = tid; idx < KC * 3 * 66; idx += 256) {
      int cc = idx / 198;
      int rem = idx - cc * 198;
      int r = rem / 66;
      int i = rem - r * 66;
      int yy = y - 1 + r;
      int xx = xb - 1 + i;
      float v = 0.f;
      if (yy >= 0 && yy < HH && xx >= 0 && xx < WW)
        v = x[(size_t)(c0 + cc) * NPIX + yy * WW + xx];
      xs[cc][r][i] = (double)v;
    }
    for (int idx = tid; idx < KC * 576; idx += 256) {
      int cc = idx / 576;
      int rem = idx - cc * 576;
      int k = rem >> 6, mm = rem & 63;
      wsm[cc][k][mm] = wt64[(size_t)((c0 + cc) * 9 + k) * 512 + m0 + mm];
    }
    __syncthreads();

    for (int cc = 0; cc < KC; ++cc) {
#pragma unroll
      for (int ky = 0; ky < 3; ++ky) {
        const double* wp0 = &wsm[cc][ky * 3 + 0][mo];
        const double* wp1 = &wsm[cc][ky * 3 + 1][mo];
        const double* wp2 = &wsm[cc][ky * 3 + 2][mo];
        double w00 = wp0[0], w01 = wp0[1], w02 = wp0[2], w03 = wp0[3];
        double w10 = wp1[0], w11 = wp1[1], w12d = wp1[2], w13 = wp1[3];
        double w20 = wp2[0], w21 = wp2[1], w22 = wp2[2], w23 = wp2[3];
        const double* xrow = &xs[cc][ky][0];
#define CONV_BODY(IP)                                                      \
  if (np > IP) {                                                           \
    int a = axr[IP];                                                       \
    double x0 = xrow[a], x1 = xrow[a + 1], x2 = xrow[a + 2];               \
    acc[IP][0] = fma(x0, w00, acc[IP][0]);                                 \
    acc[IP][1] = fma(x0, w01, acc[IP][1]);                                 \
    acc[IP][2] = fma(x0, w02, acc[IP][2]);                                 \
    acc[IP][3] = fma(x0, w03, acc[IP][3]);                                 \
    acc[IP][0] = fma(x1, w10, acc[IP][0]);                                 \
    acc[IP][1] = fma(x1, w11, acc[IP][1]);                                 \
    acc[IP][2] = fma(x1, w12d, acc[IP][2]);                                \
    acc[IP][3] = fma(x1, w13, acc[IP][3]);                                 \
    acc[IP][0] = fma(x2, w20, acc[IP][0]);                                 \
    acc[IP][1] = fma(x2, w21, acc[IP][1]);                                 \
    acc[IP][2] = fma(x2, w22, acc[IP][2]);                                 \
    acc[IP][3] = fma(x2, w23, acc[IP][3]);                                 \
  }
        CONV_BODY(0)
        CONV_BODY(1)
        CONV_BODY(2)
        CONV_BODY(3)
#undef CONV_BODY
      }
    }
    __syncthreads();
  }

  // fp32 h epilogue (per-op; mask==1 for active pixels so *mask is a no-op)
  float4 bv = *(const float4*)&bias[m0 + mo];
  float hv[4][4];
#pragma unroll
  for (int ip = 0; ip < 4; ++ip) {
    if (ip < np) {
      hv[ip][0] = fmaxf(__fadd_rn((float)acc[ip][0], bv.x), 0.f);
      hv[ip][1] = fmaxf(__fadd_rn((float)acc[ip][1], bv.y), 0.f);
      hv[ip][2] = fmaxf(__fadd_rn((float)acc[ip][2], bv.z), 0.f);
      hv[ip][3] = fmaxf(__fadd_rn((float)acc[ip][3], bv.w), 0.f);
    }
  }

  // 12 head partial dots (f64 over fp32 h), shuffle-reduce over 16 tm lanes
#pragma unroll
  for (int r = 0; r < 12; ++r) {
    const float* wr = &w12[r][mo];
    double w0 = (double)wr[0], w1 = (double)wr[1];
    double w2 = (double)wr[2], w3 = (double)wr[3];
#pragma unroll
    for (int ip = 0; ip < 4; ++ip) {
      if (ip < np) {
        double t = (double)hv[ip][0] * w0 + (double)hv[ip][1] * w1 +
                   (double)hv[ip][2] * w2 + (double)hv[ip][3] * w3;
#pragma unroll
        for (int off = 8; off; off >>= 1) t += __shfl_down(t, off, 16);
        if (tm == 0) {
          int pix = y * WW + xb + axr[ip];
          atomicAdd(&logits[(size_t)pix * 12 + r], t);
        }
      }
    }
  }
}

// ------- finalize per pixel: f64 softmax/argmax/sigmoid, cast to f32 ----------
__global__ __launch_bounds__(256) void finalize_kernel(
    const double* __restrict__ logits, const float* __restrict__ loc_b,
    const float* __restrict__ cls_b, const float* __restrict__ cos_b,
    float* __restrict__ out, float* __restrict__ fg32,
    float* __restrict__ ascale, int* __restrict__ assign) {
  int p = blockIdx.x * 256 + threadIdx.x;
  const double* lg = &logits[(size_t)p * 12];
#pragma unroll
  for (int o = 0; o < 4; ++o)
    out[O_LOCS + p * 4 + o] = (float)(lg[o] + (double)loc_b[o]);
  double cl[7];
#pragma unroll
  for (int i = 0; i < 7; ++i) {
    cl[i] = lg[4 + i] + (double)cls_b[i];
    out[O_CLS + p * 7 + i] = (float)cl[i];
  }
  double z = lg[11] + (double)cos_b[0];
  double sig = 1.0 / (1.0 + exp(-z));
  out[O_COS + p] = (float)sig;
  double pm = cl[0];
  int ai = 0;
#pragma unroll
  for (int i = 1; i < 7; ++i)
    if (cl[i] > pm) { pm = cl[i]; ai = i; }
  double mx = cl[0];
#pragma unroll
  for (int i = 1; i < 7; ++i) mx = fmax(mx, cl[i]);
  double S = 0.0;
#pragma unroll
  for (int i = 0; i < 7; ++i) S += exp(cl[i] - mx);
  double p0 = exp(cl[0] - mx) / S;
  fg32[p] = (float)(1.0 - p0);
  assign[p] = ai;
  const float BS[7] = {16.f, 9.f, 14.f, 21.f, 33.f, 54.f, 93.f};
  ascale[p] = BS[ai];
}

// -------- anchors, loc2bbox, clip, validity, scores — fp32 op-for-op ----------
__global__ __launch_bounds__(256) void roi_kernel(
    float* __restrict__ out, const float* __restrict__ fg32,
    const float* __restrict__ ascale, const int* __restrict__ assign,
    const int* __restrict__ img_h, const int* __restrict__ img_w,
    float* __restrict__ roi, float* __restrict__ scores32) {
  int p = blockIdx.x * 256 + threadIdx.x;
  float a0 = out[O_COS + 0];
  if (a0 == 0.0f) a0 = __fadd_rn(a0, 1e-5f);
  float t1 = __fmul_rn(a0, a0);
  float t2 = __fdiv_rn(1.0f, t1);
  float t3 = __fsub_rn(t2, 1.0f);
  float anchor_h = __fmul_rn(ascale[0], sqrt32(t3));
  float anchor_w = ascale[p];
  float ay = __fadd_rn((float)(p >> 7) * 8.0f, 4.0f);
  float ax = __fadd_rn((float)(p & 127) * 8.0f, 4.0f);
  float A0 = __fsub_rn(ay, __fmul_rn(0.5f, anchor_h));
  float A1 = __fsub_rn(ax, __fmul_rn(0.5f, anchor_w));
  float A2 = __fadd_rn(ay, __fmul_rn(0.5f, anchor_h));
  float A3 = __fadd_rn(ax, __fmul_rn(0.5f, anchor_w));
  *(float4*)&out[O_ANCHOR + p * 4] = make_float4(A0, A1, A2, A3);
  float hA = __fsub_rn(A2, A0), wA = __fsub_rn(A3, A1);
  float cy = __fadd_rn(A0, __fmul_rn(0.5f, hA));
  float cx = __fadd_rn(A1, __fmul_rn(0.5f, wA));
  float l0 = out[O_LOCS + p * 4 + 0], l1 = out[O_LOCS + p * 4 + 1];
  float l2 = out[O_LOCS + p * 4 + 2], l3 = out[O_LOCS + p * 4 + 3];
  float ncy = __fadd_rn(__fmul_rn(l0, hA), cy);
  float ncx = __fadd_rn(__fmul_rn(l1, wA), cx);
  float nh = __fmul_rn(exp32(l2), hA);
  float nw = __fmul_rn(exp32(l3), wA);
  float b0 = __fsub_rn(ncy, __fmul_rn(0.5f, nh));
  float b1 = __fsub_rn(ncx, __fmul_rn(0.5f, nw));
  float b2 = __fadd_rn(ncy, __fmul_rn(0.5f, nh));
  float b3 = __fadd_rn(ncx, __fmul_rn(0.5f, nw));
  float IH = (float)img_h[0], IW = (float)img_w[0];
  b0 = fminf(fmaxf(b0, 0.f), IH);
  b1 = fminf(fmaxf(b1, 0.f), IW);
  b2 = fminf(fmaxf(b2, 0.f), IH);
  b3 = fminf(fmaxf(b3, 0.f), IW);
  *(float4*)&roi[p * 4] = make_float4(b0, b1, b2, b3);
  float hs = __fsub_rn(b2, b0), wd = __fsub_rn(b3, b1);
  bool valid = (assign[p] > 0) && (hs >= 16.f) && (wd >= 16.f);
  scores32[p] = valid ? fg32[p] : -INFINITY;
}

// ----- stable descending sort (bitonic) on fp32 score bits + index asc -------
__global__ __launch_bounds__(1024) void sort_kernel(
    const float* __restrict__ scores32, const float* __restrict__ roi,
    float* __restrict__ out, float* __restrict__ cand, float* __restrict__ tops) {
  __shared__ unsigned long long keys[16384];
  int tid = threadIdx.x;
  for (int i = tid; i < 16384; i += 1024) {
    unsigned u = __float_as_uint(scores32[i]);
    u = (u & 0x80000000u) ? ~u : (u | 0x80000000u);
    keys[i] = ((unsigned long long)(~u) << 32) | (unsigned)i;
  }
  __syncthreads();
  for (int k = 2; k <= 16384; k <<= 1) {
    for (int j = k >> 1; j > 0; j >>= 1) {
      for (int i = tid; i < 16384; i += 1024) {
        int l = i ^ j;
        if (l > i) {
          unsigned long long a = keys[i], b = keys[l];
          bool up = ((i & k) == 0);
          if ((a > b) == up) { keys[i] = b; keys[l] = a; }
        }
      }
      __syncthreads();
    }
  }
  for (int t = tid; t < NPRE; t += 1024) {
    int idx = (int)(keys[t] & 0x3FFFull);
    float s = scores32[idx];
    float4 b = make_float4(0.f, 0.f, 0.f, 0.f);
    if (isfinite(s)) b = *(const float4*)&roi[idx * 4];
    ((float4*)(out + O_OLD))[t] = b;
    ((float4*)cand)[t] = b;
    tops[t] = s;
  }
}

// --- sequential NMS: boxes in immutable LDS, live scores in registers,
// --- fused suppress+argmax pass, 2 barriers/iter, fp32 op-for-op --------------
__global__ __launch_bounds__(1024) void nms_kernel(const float* __restrict__ cand,
                                                   const float* __restrict__ tops,
                                                   float* __restrict__ out) {
  __shared__ float sy0[NPRE], sx0[NPRE], sy1[NPRE], sx1[NPRE], sar[NPRE], ssc[NPRE];
  __shared__ unsigned long long red[16];
  __shared__ unsigned long long bestk_s;
  int tid = threadIdx.x;
  float rsc[6];
#pragma unroll
  for (int j = 0; j < 6; ++j) {
    int i = tid + j * 1024;
    if (i < NPRE) {
      float4 b = ((const float4*)cand)[i];
      float s = tops[i];
      float ar = __fmul_rn(__fsub_rn(b.z, b.x), __fsub_rn(b.w, b.y));
      sy0[i] = b.x; sx0[i] = b.y; sy1[i] = b.z; sx1[i] = b.w;
      sar[i] = ar; ssc[i] = s;
      rsc[j] = s;
    } else {
      rsc[j] = -INFINITY;
    }
  }
  __syncthreads();
  int lane = tid & 63, wid = tid >> 6;
  float py0 = 0.f, px0 = 0.f, py1 = 0.f, px1 = 0.f, par = 0.f;
  bool havepick = false;
  for (int k = 0; k < NPOST; ++k) {
    unsigned long long best = 0;
#pragma unroll
    for (int j = 0; j < 6; ++j) {
      int i = tid + j * 1024;
      if (i < NPRE) {
        float s = rsc[j];
        if (havepick && s != -INFINITY) {
          float yy0 = fmaxf(sy0[i], py0), xx0 = fmaxf(sx0[i], px0);
          float yy1 = fminf(sy1[i], py1), xx1 = fminf(sx1[i], px1);
          float inter = __fmul_rn(fmaxf(__fsub_rn(yy1, yy0), 0.f),
                                  fmaxf(__fsub_rn(xx1, xx0), 0.f));
          float den = __fadd_rn(__fsub_rn(__fadd_rn(sar[i], par), inter), 1e-9f);
          float iou = __fdiv_rn(inter, den);
          if (iou > 0.7f) { rsc[j] = -INFINITY; s = -INFINITY; }
        }
        unsigned u = __float_as_uint(s);
        u = (u & 0x80000000u) ? ~u : (u | 0x80000000u);
        unsigned long long key =
            ((unsigned long long)u << 32) | (unsigned)(NPRE - i);
        if (key > best) best = key;
      }
    }
#pragma unroll
    for (int off = 32; off; off >>= 1) {
      unsigned long long o = __shfl_xor(best, off, 64);
      if (o > best) best = o;
    }
    if (lane == 0) red[wid] = best;
    __syncthreads();
    if (tid == 0) {
      unsigned long long b = red[0];
      for (int w2 = 1; w2 < 16; ++w2)
        if (red[w2] > b) b = red[w2];
      bestk_s = b;
    }
    __syncthreads();
    unsigned long long b = bestk_s;
    int i = NPRE - (int)(b & 0xFFFFFFFFull);
    bool valid = (unsigned)(b >> 32) > 0x007FFFFFu;
    py0 = sy0[i]; px0 = sx0[i]; py1 = sy1[i]; px1 = sx1[i]; par = sar[i];
    havepick = true;
    if (tid == 0) {
      if (valid) {
        out[O_ROIS + k * 4 + 0] = py0;
        out[O_ROIS + k * 4 + 1] = px0;
        out[O_ROIS + k * 4 + 2] = py1;
        out[O_ROIS + k * 4 + 3] = px1;
        out[O_RSC + k] = ssc[i];
      } else {
        out[O_ROIS + k * 4 + 0] = 0.f;
        out[O_ROIS + k * 4 + 1] = 0.f;
        out[O_ROIS + k * 4 + 2] = 0.f;
        out[O_ROIS + k * 4 + 3] = 0.f;
        out[O_RSC + k] = 0.f;
      }
    }
  }
  for (int t = tid; t < NPOST; t += 1024) out[O_RIDX + t] = 0.f;
}

extern "C" void kernel_launch(void* const* d_in, const int* in_sizes, int n_in,
                              void* d_out, int out_size, void* d_ws, size_t ws_size,
                              hipStream_t stream) {
  (void)in_sizes; (void)n_in; (void)out_size; (void)ws_size;
  const float* x      = (const float*)d_in[0];
  const int*   skel   = (const int*)d_in[1];
  const float* conv_w = (const float*)d_in[2];
  const float* conv_b = (const float*)d_in[3];
  const float* loc_w  = (const float*)d_in[4];
  const float* loc_b  = (const float*)d_in[5];
  const float* cls_w  = (const float*)d_in[6];
  const float* cls_b  = (const float*)d_in[7];
  const float* cos_w  = (const float*)d_in[8];
  const float* cos_b  = (const float*)d_in[9];
  const int*   img_h  = (const int*)d_in[10];
  const int*   img_w  = (const int*)d_in[11];
  float* out = (float*)d_out;
  float* ws  = (float*)d_ws;

  double* wt64     = (double*)(ws + WS_WT64);
  double* logits   = (double*)(ws + WS_LOG);
  float*  fg32     = ws + WS_FG32;
  float*  ascale   = ws + WS_ASCALE;
  int*    assign   = (int*)(ws + WS_ASSIGN);
  float*  roi      = ws + WS_ROI;
  float*  scores32 = ws + WS_SC32;
  float*  cand     = ws + WS_CAND;
  float*  tops     = ws + WS_TOPS;

  hipLaunchKernelGGL(zero_kernel, dim3(192), dim3(1024), 0, stream, logits, NPIX * 12);
  hipLaunchKernelGGL(wt_kernel, dim3(72, 8), dim3(256), 0, stream, conv_w, wt64);
  hipLaunchKernelGGL(conv_heads_kernel, dim3(256, 8), dim3(256), 0, stream, x, wt64,
                     conv_b, skel, loc_w, cls_w, cos_w, logits);
  hipLaunchKernelGGL(finalize_kernel, dim3(64), dim3(256), 0, stream, logits, loc_b,
                     cls_b, cos_b, out, fg32, ascale, assign);
  hipLaunchKernelGGL(roi_kernel, dim3(64), dim3(256), 0, stream, out, fg32, ascale,
                     assign, img_h, img_w, roi, scores32);
  hipLaunchKernelGGL(sort_kernel, dim3(1), dim3(1024), 0, stream, scores32, roi, out,
                     cand, tops);
  hipLaunchKernelGGL(nms_kernel, dim3(1), dim3(1024), 0, stream, cand, tops, out);
}

// Round 11
// 3391.670 us; speedup vs baseline: 1.0344x; 1.0344x over previous
//
#include <hip/hip_runtime.h>
#include <math.h>

#define HH 128
#define WW 128
#define CIN 512
#define NPIX 16384
#define NPRE 6000
#define NPOST 300

// workspace offsets (floats; WT64/LOG are doubles at even offsets)
#define WS_WT64   0ull                        // 2359296 doubles = 4718592 floats
#define WS_LOG    4718592ull                  // 16384*12 doubles = 393216 floats
#define WS_FG32   5111808ull                  // 16384
#define WS_ASCALE 5128192ull                  // 16384
#define WS_ASSIGN 5144576ull                  // 16384 (int)
#define WS_ROI    5160960ull                  // 16384*4
#define WS_SC32   5226496ull                  // 16384
#define WS_CAND   5242880ull                  // 6000*4
#define WS_TOPS   5266880ull                  // 6000

// d_out offsets (floats), concatenated tuple in return order
#define O_LOCS   0
#define O_ROIS   65536
#define O_RIDX   66736
#define O_ANCHOR 67036
#define O_CLS    132572
#define O_COS    247260
#define O_RSC    263644
#define O_OLD    263944

__device__ __forceinline__ float exp32(float x) { return (float)exp((double)x); }
__device__ __forceinline__ float sqrt32(float x) { return (float)sqrt((double)x); }

__global__ __launch_bounds__(1024) void zero_kernel(double* __restrict__ p, int n) {
  int i = blockIdx.x * 1024 + threadIdx.x;
  if (i < n) p[i] = 0.0;
}

// ------- weight transpose+convert: w[m][c][k] (f32) -> wt64[(c*9+k)][m] (f64) --
__global__ __launch_bounds__(256) void wt_kernel(const float* __restrict__ w,
                                                 double* __restrict__ wt64) {
  __shared__ float t[64][65];
  int ck0 = blockIdx.x * 64;
  int m0  = blockIdx.y * 64;
  int j  = threadIdx.x & 63;
  int i0 = threadIdx.x >> 6;
#pragma unroll
  for (int ii = 0; ii < 16; ++ii) {
    int i = i0 + ii * 4;
    t[i][j] = w[(size_t)(m0 + i) * 4608 + ck0 + j];
  }
  __syncthreads();
#pragma unroll
  for (int ii = 0; ii < 16; ++ii) {
    int jj = i0 + ii * 4;
    wt64[(size_t)(ck0 + jj) * 512 + m0 + j] = (double)t[j][jj];
  }
}

// -- fused conv 3x3 (fp64 acc, bit-identical (c,ky,kx) chain) on ACTIVE pixels:
// -- x staged f32 in LDS (conflict-free), weights f64 straight from global ----
#define KC 8
__global__ __launch_bounds__(256) void conv_heads_kernel(
    const float* __restrict__ x, const double* __restrict__ wt64,
    const float* __restrict__ bias, const int* __restrict__ mask,
    const float* __restrict__ loc_w, const float* __restrict__ cls_w,
    const float* __restrict__ cos_w, double* __restrict__ logits) {
  __shared__ float xs[KC][3][66];    // 6.3 KB
  __shared__ float w12[12][64];      // 3 KB
  __shared__ int act[64];
  __shared__ int nact_s;
  int tid = threadIdx.x;
  int tm = tid & 15, tp = tid >> 4;
  int seg = blockIdx.x;  // 0..255
  int mt = blockIdx.y;   // 0..7
  int y = seg >> 1, xb = (seg & 1) << 6;
  int m0 = mt << 6;
  int mo = tm << 2;

  for (int idx = tid; idx < 12 * 64; idx += 256) {
    int r = idx >> 6, c = idx & 63;
    float v = (r < 4) ? loc_w[r * 512 + m0 + c]
                      : (r < 11) ? cls_w[(r - 4) * 512 + m0 + c] : cos_w[m0 + c];
    w12[r][c] = v;
  }
  if (tid < 64) {
    int mval = mask[y * WW + xb + tid];
    unsigned long long bal = __ballot(mval != 0);
    if (mval) {
      int pos = __popcll(bal & ((1ull << tid) - 1ull));
      act[pos] = tid;
    }
    if (tid == 0) nact_s = (int)__popcll(bal);
  }
  __syncthreads();
  int n_act = nact_s;
  int np = 0;
  int axr[4] = {0, 0, 0, 0};
#pragma unroll
  for (int ip = 0; ip < 4; ++ip) {
    int slot = tp + (ip << 4);
    if (slot < n_act) { axr[ip] = act[slot]; np = ip + 1; }
  }

  double acc[4][4];
#pragma unroll
  for (int a = 0; a < 4; ++a)
#pragma unroll
    for (int b = 0; b < 4; ++b) acc[a][b] = 0.0;

  const double* wbase = wt64 + m0 + mo;
  for (int c0 = 0; c0 < CIN; c0 += KC) {
    for (int idx = tid; idx < KC * 3 * 66; idx += 256) {
      int cc = idx / 198;
      int rem = idx - cc * 198;
      int r = rem / 66;
      int i = rem - r * 66;
      int yy = y - 1 + r;
      int xx = xb - 1 + i;
      float v = 0.f;
      if (yy >= 0 && yy < HH && xx >= 0 && xx < WW)
        v = x[(size_t)(c0 + cc) * NPIX + yy * WW + xx];
      xs[cc][r][i] = v;
    }
    __syncthreads();

    for (int cc = 0; cc < KC; ++cc) {
      const double* wck = wbase + (size_t)((c0 + cc) * 9) * 512;
#pragma unroll
      for (int ky = 0; ky < 3; ++ky) {
        const double* wg = wck + (size_t)(ky * 3) * 512;
        double2 wa0 = *(const double2*)&wg[0];
        double2 wa1 = *(const double2*)&wg[2];
        double2 wb0 = *(const double2*)&wg[512];
        double2 wb1 = *(const double2*)&wg[514];
        double2 wc0 = *(const double2*)&wg[1024];
        double2 wc1 = *(const double2*)&wg[1026];
        const float* xrow = &xs[cc][ky][0];
#define CONV_BODY(IP)                                                      \
  if (np > IP) {                                                           \
    int a = axr[IP];                                                       \
    double x0 = (double)xrow[a];                                           \
    double x1 = (double)xrow[a + 1];                                       \
    double x2 = (double)xrow[a + 2];                                       \
    acc[IP][0] = fma(x0, wa0.x, acc[IP][0]);                               \
    acc[IP][1] = fma(x0, wa0.y, acc[IP][1]);                               \
    acc[IP][2] = fma(x0, wa1.x, acc[IP][2]);                               \
    acc[IP][3] = fma(x0, wa1.y, acc[IP][3]);                               \
    acc[IP][0] = fma(x1, wb0.x, acc[IP][0]);                               \
    acc[IP][1] = fma(x1, wb0.y, acc[IP][1]);                               \
    acc[IP][2] = fma(x1, wb1.x, acc[IP][2]);                               \
    acc[IP][3] = fma(x1, wb1.y, acc[IP][3]);                               \
    acc[IP][0] = fma(x2, wc0.x, acc[IP][0]);                               \
    acc[IP][1] = fma(x2, wc0.y, acc[IP][1]);                               \
    acc[IP][2] = fma(x2, wc1.x, acc[IP][2]);                               \
    acc[IP][3] = fma(x2, wc1.y, acc[IP][3]);                               \
  }
        CONV_BODY(0)
        CONV_BODY(1)
        CONV_BODY(2)
        CONV_BODY(3)
#undef CONV_BODY
      }
    }
    __syncthreads();
  }

  // fp32 h epilogue (per-op; mask==1 for active pixels so *mask is a no-op)
  float4 bv = *(const float4*)&bias[m0 + mo];
  float hv[4][4];
#pragma unroll
  for (int ip = 0; ip < 4; ++ip) {
    if (ip < np) {
      hv[ip][0] = fmaxf(__fadd_rn((float)acc[ip][0], bv.x), 0.f);
      hv[ip][1] = fmaxf(__fadd_rn((float)acc[ip][1], bv.y), 0.f);
      hv[ip][2] = fmaxf(__fadd_rn((float)acc[ip][2], bv.z), 0.f);
      hv[ip][3] = fmaxf(__fadd_rn((float)acc[ip][3], bv.w), 0.f);
    }
  }

  // 12 head partial dots (f64 over fp32 h), shuffle-reduce over 16 tm lanes
#pragma unroll
  for (int r = 0; r < 12; ++r) {
    const float* wr = &w12[r][mo];
    double w0 = (double)wr[0], w1 = (double)wr[1];
    double w2 = (double)wr[2], w3 = (double)wr[3];
#pragma unroll
    for (int ip = 0; ip < 4; ++ip) {
      if (ip < np) {
        double t = (double)hv[ip][0] * w0 + (double)hv[ip][1] * w1 +
                   (double)hv[ip][2] * w2 + (double)hv[ip][3] * w3;
#pragma unroll
        for (int off = 8; off; off >>= 1) t += __shfl_down(t, off, 16);
        if (tm == 0) {
          int pix = y * WW + xb + axr[ip];
          atomicAdd(&logits[(size_t)pix * 12 + r], t);
        }
      }
    }
  }
}

// ------- finalize per pixel: f64 softmax/argmax/sigmoid, cast to f32 ----------
__global__ __launch_bounds__(256) void finalize_kernel(
    const double* __restrict__ logits, const float* __restrict__ loc_b,
    const float* __restrict__ cls_b, const float* __restrict__ cos_b,
    float* __restrict__ out, float* __restrict__ fg32,
    float* __restrict__ ascale, int* __restrict__ assign) {
  int p = blockIdx.x * 256 + threadIdx.x;
  const double* lg = &logits[(size_t)p * 12];
#pragma unroll
  for (int o = 0; o < 4; ++o)
    out[O_LOCS + p * 4 + o] = (float)(lg[o] + (double)loc_b[o]);
  double cl[7];
#pragma unroll
  for (int i = 0; i < 7; ++i) {
    cl[i] = lg[4 + i] + (double)cls_b[i];
    out[O_CLS + p * 7 + i] = (float)cl[i];
  }
  double z = lg[11] + (double)cos_b[0];
  double sig = 1.0 / (1.0 + exp(-z));
  out[O_COS + p] = (float)sig;
  double pm = cl[0];
  int ai = 0;
#pragma unroll
  for (int i = 1; i < 7; ++i)
    if (cl[i] > pm) { pm = cl[i]; ai = i; }
  double mx = cl[0];
#pragma unroll
  for (int i = 1; i < 7; ++i) mx = fmax(mx, cl[i]);
  double S = 0.0;
#pragma unroll
  for (int i = 0; i < 7; ++i) S += exp(cl[i] - mx);
  double p0 = exp(cl[0] - mx) / S;
  fg32[p] = (float)(1.0 - p0);
  assign[p] = ai;
  const float BS[7] = {16.f, 9.f, 14.f, 21.f, 33.f, 54.f, 93.f};
  ascale[p] = BS[ai];
}

// -------- anchors, loc2bbox, clip, validity, scores — fp32 op-for-op ----------
__global__ __launch_bounds__(256) void roi_kernel(
    float* __restrict__ out, const float* __restrict__ fg32,
    const float* __restrict__ ascale, const int* __restrict__ assign,
    const int* __restrict__ img_h, const int* __restrict__ img_w,
    float* __restrict__ roi, float* __restrict__ scores32) {
  int p = blockIdx.x * 256 + threadIdx.x;
  float a0 = out[O_COS + 0];
  if (a0 == 0.0f) a0 = __fadd_rn(a0, 1e-5f);
  float t1 = __fmul_rn(a0, a0);
  float t2 = __fdiv_rn(1.0f, t1);
  float t3 = __fsub_rn(t2, 1.0f);
  float anchor_h = __fmul_rn(ascale[0], sqrt32(t3));
  float anchor_w = ascale[p];
  float ay = __fadd_rn((float)(p >> 7) * 8.0f, 4.0f);
  float ax = __fadd_rn((float)(p & 127) * 8.0f, 4.0f);
  float A0 = __fsub_rn(ay, __fmul_rn(0.5f, anchor_h));
  float A1 = __fsub_rn(ax, __fmul_rn(0.5f, anchor_w));
  float A2 = __fadd_rn(ay, __fmul_rn(0.5f, anchor_h));
  float A3 = __fadd_rn(ax, __fmul_rn(0.5f, anchor_w));
  *(float4*)&out[O_ANCHOR + p * 4] = make_float4(A0, A1, A2, A3);
  float hA = __fsub_rn(A2, A0), wA = __fsub_rn(A3, A1);
  float cy = __fadd_rn(A0, __fmul_rn(0.5f, hA));
  float cx = __fadd_rn(A1, __fmul_rn(0.5f, wA));
  float l0 = out[O_LOCS + p * 4 + 0], l1 = out[O_LOCS + p * 4 + 1];
  float l2 = out[O_LOCS + p * 4 + 2], l3 = out[O_LOCS + p * 4 + 3];
  float ncy = __fadd_rn(__fmul_rn(l0, hA), cy);
  float ncx = __fadd_rn(__fmul_rn(l1, wA), cx);
  float nh = __fmul_rn(exp32(l2), hA);
  float nw = __fmul_rn(exp32(l3), wA);
  float b0 = __fsub_rn(ncy, __fmul_rn(0.5f, nh));
  float b1 = __fsub_rn(ncx, __fmul_rn(0.5f, nw));
  float b2 = __fadd_rn(ncy, __fmul_rn(0.5f, nh));
  float b3 = __fadd_rn(ncx, __fmul_rn(0.5f, nw));
  float IH = (float)img_h[0], IW = (float)img_w[0];
  b0 = fminf(fmaxf(b0, 0.f), IH);
  b1 = fminf(fmaxf(b1, 0.f), IW);
  b2 = fminf(fmaxf(b2, 0.f), IH);
  b3 = fminf(fmaxf(b3, 0.f), IW);
  *(float4*)&roi[p * 4] = make_float4(b0, b1, b2, b3);
  float hs = __fsub_rn(b2, b0), wd = __fsub_rn(b3, b1);
  bool valid = (assign[p] > 0) && (hs >= 16.f) && (wd >= 16.f);
  scores32[p] = valid ? fg32[p] : -INFINITY;
}

// ----- stable descending sort (bitonic) on fp32 score bits + index asc -------
__global__ __launch_bounds__(1024) void sort_kernel(
    const float* __restrict__ scores32, const float* __restrict__ roi,
    float* __restrict__ out, float* __restrict__ cand, float* __restrict__ tops) {
  __shared__ unsigned long long keys[16384];
  int tid = threadIdx.x;
  for (int i = tid; i < 16384; i += 1024) {
    unsigned u = __float_as_uint(scores32[i]);
    u = (u & 0x80000000u) ? ~u : (u | 0x80000000u);
    keys[i] = ((unsigned long long)(~u) << 32) | (unsigned)i;
  }
  __syncthreads();
  for (int k = 2; k <= 16384; k <<= 1) {
    for (int j = k >> 1; j > 0; j >>= 1) {
      for (int i = tid; i < 16384; i += 1024) {
        int l = i ^ j;
        if (l > i) {
          unsigned long long a = keys[i], b = keys[l];
          bool up = ((i & k) == 0);
          if ((a > b) == up) { keys[i] = b; keys[l] = a; }
        }
      }
      __syncthreads();
    }
  }
  for (int t = tid; t < NPRE; t += 1024) {
    int idx = (int)(keys[t] & 0x3FFFull);
    float s = scores32[idx];
    float4 b = make_float4(0.f, 0.f, 0.f, 0.f);
    if (isfinite(s)) b = *(const float4*)&roi[idx * 4];
    ((float4*)(out + O_OLD))[t] = b;
    ((float4*)cand)[t] = b;
    tops[t] = s;
  }
}

// --- sequential NMS: boxes in immutable LDS, live scores in registers,
// --- fused suppress+argmax pass, 2 barriers/iter, fp32 op-for-op --------------
__global__ __launch_bounds__(1024) void nms_kernel(const float* __restrict__ cand,
                                                   const float* __restrict__ tops,
                                                   float* __restrict__ out) {
  __shared__ float sy0[NPRE], sx0[NPRE], sy1[NPRE], sx1[NPRE], sar[NPRE], ssc[NPRE];
  __shared__ unsigned long long red[16];
  __shared__ unsigned long long bestk_s;
  int tid = threadIdx.x;
  float rsc[6];
#pragma unroll
  for (int j = 0; j < 6; ++j) {
    int i = tid + j * 1024;
    if (i < NPRE) {
      float4 b = ((const float4*)cand)[i];
      float s = tops[i];
      float ar = __fmul_rn(__fsub_rn(b.z, b.x), __fsub_rn(b.w, b.y));
      sy0[i] = b.x; sx0[i] = b.y; sy1[i] = b.z; sx1[i] = b.w;
      sar[i] = ar; ssc[i] = s;
      rsc[j] = s;
    } else {
      rsc[j] = -INFINITY;
    }
  }
  __syncthreads();
  int lane = tid & 63, wid = tid >> 6;
  float py0 = 0.f, px0 = 0.f, py1 = 0.f, px1 = 0.f, par = 0.f;
  bool havepick = false;
  for (int k = 0; k < NPOST; ++k) {
    unsigned long long best = 0;
#pragma unroll
    for (int j = 0; j < 6; ++j) {
      int i = tid + j * 1024;
      if (i < NPRE) {
        float s = rsc[j];
        if (havepick && s != -INFINITY) {
          float yy0 = fmaxf(sy0[i], py0), xx0 = fmaxf(sx0[i], px0);
          float yy1 = fminf(sy1[i], py1), xx1 = fminf(sx1[i], px1);
          float inter = __fmul_rn(fmaxf(__fsub_rn(yy1, yy0), 0.f),
                                  fmaxf(__fsub_rn(xx1, xx0), 0.f));
          float den = __fadd_rn(__fsub_rn(__fadd_rn(sar[i], par), inter), 1e-9f);
          float iou = __fdiv_rn(inter, den);
          if (iou > 0.7f) { rsc[j] = -INFINITY; s = -INFINITY; }
        }
        unsigned u = __float_as_uint(s);
        u = (u & 0x80000000u) ? ~u : (u | 0x80000000u);
        unsigned long long key =
            ((unsigned long long)u << 32) | (unsigned)(NPRE - i);
        if (key > best) best = key;
      }
    }
#pragma unroll
    for (int off = 32; off; off >>= 1) {
      unsigned long long o = __shfl_xor(best, off, 64);
      if (o > best) best = o;
    }
    if (lane == 0) red[wid] = best;
    __syncthreads();
    if (tid == 0) {
      unsigned long long b = red[0];
      for (int w2 = 1; w2 < 16; ++w2)
        if (red[w2] > b) b = red[w2];
      bestk_s = b;
    }
    __syncthreads();
    unsigned long long b = bestk_s;
    int i = NPRE - (int)(b & 0xFFFFFFFFull);
    bool valid = (unsigned)(b >> 32) > 0x007FFFFFu;
    py0 = sy0[i]; px0 = sx0[i]; py1 = sy1[i]; px1 = sx1[i]; par = sar[i];
    havepick = true;
    if (tid == 0) {
      if (valid) {
        out[O_ROIS + k * 4 + 0] = py0;
        out[O_ROIS + k * 4 + 1] = px0;
        out[O_ROIS + k * 4 + 2] = py1;
        out[O_ROIS + k * 4 + 3] = px1;
        out[O_RSC + k] = ssc[i];
      } else {
        out[O_ROIS + k * 4 + 0] = 0.f;
        out[O_ROIS + k * 4 + 1] = 0.f;
        out[O_ROIS + k * 4 + 2] = 0.f;
        out[O_ROIS + k * 4 + 3] = 0.f;
        out[O_RSC + k] = 0.f;
      }
    }
  }
  for (int t = tid; t < NPOST; t += 1024) out[O_RIDX + t] = 0.f;
}

extern "C" void kernel_launch(void* const* d_in, const int* in_sizes, int n_in,
                              void* d_out, int out_size, void* d_ws, size_t ws_size,
                              hipStream_t stream) {
  (void)in_sizes; (void)n_in; (void)out_size; (void)ws_size;
  const float* x      = (const float*)d_in[0];
  const int*   skel   = (const int*)d_in[1];
  const float* conv_w = (const float*)d_in[2];
  const float* conv_b = (const float*)d_in[3];
  const float* loc_w  = (const float*)d_in[4];
  const float* loc_b  = (const float*)d_in[5];
  const float* cls_w  = (const float*)d_in[6];
  const float* cls_b  = (const float*)d_in[7];
  const float* cos_w  = (const float*)d_in[8];
  const float* cos_b  = (const float*)d_in[9];
  const int*   img_h  = (const int*)d_in[10];
  const int*   img_w  = (const int*)d_in[11];
  float* out = (float*)d_out;
  float* ws  = (float*)d_ws;

  double* wt64     = (double*)(ws + WS_WT64);
  double* logits   = (double*)(ws + WS_LOG);
  float*  fg32     = ws + WS_FG32;
  float*  ascale   = ws + WS_ASCALE;
  int*    assign   = (int*)(ws + WS_ASSIGN);
  float*  roi      = ws + WS_ROI;
  float*  scores32 = ws + WS_SC32;
  float*  cand     = ws + WS_CAND;
  float*  tops     = ws + WS_TOPS;

  hipLaunchKernelGGL(zero_kernel, dim3(192), dim3(1024), 0, stream, logits, NPIX * 12);
  hipLaunchKernelGGL(wt_kernel, dim3(72, 8), dim3(256), 0, stream, conv_w, wt64);
  hipLaunchKernelGGL(conv_heads_kernel, dim3(256, 8), dim3(256), 0, stream, x, wt64,
                     conv_b, skel, loc_w, cls_w, cos_w, logits);
  hipLaunchKernelGGL(finalize_kernel, dim3(64), dim3(256), 0, stream, logits, loc_b,
                     cls_b, cos_b, out, fg32, ascale, assign);
  hipLaunchKernelGGL(roi_kernel, dim3(64), dim3(256), 0, stream, out, fg32, ascale,
                     assign, img_h, img_w, roi, scores32);
  hipLaunchKernelGGL(sort_kernel, dim3(1), dim3(1024), 0, stream, scores32, roi, out,
                     cand, tops);
  hipLaunchKernelGGL(nms_kernel, dim3(1), dim3(1024), 0, stream, cand, tops, out);
}